// Round 5
// baseline (84.565 us; speedup 1.0000x reference)
//
#include <hip/hip_runtime.h>
#include <cstddef>

#define EPS 1e-6f
constexpr float INV_SQRT_E = 0.6065306597126334f;  // exp(-0.5*THETA^2), THETA=1

// R18: TH=16 chain-walk restructure. Kernel is LDS-issue bound (~51k cyc/CU
// ledger matches ~22us kernel; R15's -13% cut partially realized under fill
// jitter). 64x16 tile => residue classes (mod D) have 4-8 in-tile rows; one
// chain of (J-1)+KS taps serves J pixels (vs pair-walk's 2):
//   - vertical: col-pair b64 chains, pass-split (s,q then log), slg plane
//     DELETED (logs once per element inside the chain).
//   - SAD: chain x col-pair b64 for D=2,4 (D*mj even => aligned); chain b32
//     for D=3. Outer mj loop unroll(1); <=16 accums (R13/R14 spill lessons).
//   - staging halo amortized over 16 rows (-33%/px).
// LDS ledger ~51k -> ~22k cyc/CU. LDS 36,864 B -> 4 blocks/CU = 32 waves/CU.
// Horizontal/epilogue: 2 explicit row blocks (named scalars, no runtime idx).

// ---- vertical chain walker (col-pair b64, two passes) ----
template <int D, int J, int TAPS, int LW, int KS>
__device__ __forceinline__ void vchain(const float* __restrict__ sx,
                                       float* __restrict__ cs2f,
                                       float* __restrict__ cs1,
                                       const int r0, const int c2)
{
    constexpr int STEP2 = D * (LW / 2);
    const float2* cx = (const float2*)(sx + r0 * LW + c2);
    float s0[J], s1[J], q0[J], q1[J];
#pragma unroll
    for (int j = 0; j < J; ++j) { s0[j] = 0.f; s1[j] = 0.f; q0[j] = 0.f; q1[j] = 0.f; }
#pragma unroll
    for (int t = 0; t < TAPS; ++t) {
        const float2 v = cx[t * STEP2];
#pragma unroll
        for (int j = 0; j < J; ++j)
            if (t >= j && t < j + KS) {
                s0[j] += v.x; s1[j] += v.y;
                q0[j] = fmaf(v.x, v.x, q0[j]);
                q1[j] = fmaf(v.y, v.y, q1[j]);
            }
    }
#pragma unroll
    for (int j = 0; j < J; ++j)
        *(float4*)&cs2f[2 * ((r0 + D * j) * LW + c2)] =
            make_float4(s0[j], q0[j], s1[j], q1[j]);
    // pass 2: on-the-fly v*log(v+eps) column sums
    float l0[J], l1[J];
#pragma unroll
    for (int j = 0; j < J; ++j) { l0[j] = 0.f; l1[j] = 0.f; }
#pragma unroll
    for (int t = 0; t < TAPS; ++t) {
        const float2 v = cx[t * STEP2];
        const float g0 = v.x * __logf(v.x + EPS);   // v=0 -> exactly 0
        const float g1 = v.y * __logf(v.y + EPS);
#pragma unroll
        for (int j = 0; j < J; ++j)
            if (t >= j && t < j + KS) { l0[j] += g0; l1[j] += g1; }
    }
#pragma unroll
    for (int j = 0; j < J; ++j)
        *(float2*)&cs1[(r0 + D * j) * LW + c2] = make_float2(l0[j], l1[j]);
}

// ---- SAD chain walker, col-pair b64 (D even) ----
template <int D, int J, int TAPS, int LW, int KS>
__device__ __forceinline__ void sadchain_pair(const float* __restrict__ sx,
                                              const float* __restrict__ muP,
                                              float* __restrict__ sadP,
                                              const int r0, const int c2)
{
    constexpr int STEP2 = D * (LW / 2);
    float m0[J], m1[J], a0[J], a1[J];
#pragma unroll
    for (int j = 0; j < J; ++j) {
        const float2 m = *(const float2*)&muP[(r0 + D * j) * 64 + c2];
        m0[j] = m.x; m1[j] = m.y; a0[j] = 0.f; a1[j] = 0.f;
    }
#pragma unroll 1
    for (int mj = 0; mj < KS; ++mj) {
        const float2* cp = (const float2*)(sx + r0 * LW + c2 + D * mj);
#pragma unroll
        for (int t = 0; t < TAPS; ++t) {
            const float2 v = cp[t * STEP2];
#pragma unroll
            for (int j = 0; j < J; ++j)
                if (t >= j && t < j + KS) {
                    a0[j] += fabsf(v.x - m0[j]);
                    a1[j] += fabsf(v.y - m1[j]);
                }
        }
    }
#pragma unroll
    for (int j = 0; j < J; ++j)
        *(float2*)&sadP[(r0 + D * j) * 64 + c2] = make_float2(a0[j], a1[j]);
}

// ---- SAD chain walker, single-col b32 (D odd) ----
template <int D, int J, int TAPS, int LW, int KS>
__device__ __forceinline__ void sadchain_scalar(const float* __restrict__ sx,
                                                const float* __restrict__ muP,
                                                float* __restrict__ sadP,
                                                const int r0, const int c)
{
    float m[J], a[J];
#pragma unroll
    for (int j = 0; j < J; ++j) { m[j] = muP[(r0 + D * j) * 64 + c]; a[j] = 0.f; }
#pragma unroll 1
    for (int mj = 0; mj < KS; ++mj) {
        const float* cp = sx + r0 * LW + c + D * mj;
#pragma unroll
        for (int t = 0; t < TAPS; ++t) {
            const float v = cp[t * D * LW];
#pragma unroll
            for (int j = 0; j < J; ++j)
                if (t >= j && t < j + KS) a[j] += fabsf(v - m[j]);
        }
    }
#pragma unroll
    for (int j = 0; j < J; ++j) sadP[(r0 + D * j) * 64 + c] = a[j];
}

template <int D>
__device__ __forceinline__ void body(const float* __restrict__ x,
                                     float* __restrict__ out,
                                     char* smem, int bc, int H, int W)
{
    constexpr int PAD = D * D;
    constexpr int KS  = 2 * D + 1;
    constexpr int K   = KS * KS;
    constexpr int TW  = 64, TH = 16;
    constexpr int LW  = TW + 2 * PAD;   // even for all D
    constexpr int LH  = TH + 2 * PAD;
    constexpr int NE  = LH * LW;        // even
    constexpr int NI2 = (NE / 2 + 511) / 512;
    constexpr float INVK = 1.0f / (float)K;
    constexpr float UNB  = (float)K / (float)(K - 1);

    float*  sx  = (float*)smem;                 // [LH*LW] v
    // D>=2 layout:
    float2* cs2 = (float2*)(sx + NE);           // [16*LW] {col_s, col_s2}
    float*  cs1 = (float*)(cs2 + 16 * LW);      // [16*LW] col_sl
    float*  muP  = (float*)cs2;                 // [16*64] alias (cs2 dead then)
    float*  sadP = muP + 16 * 64;               // [16*64] (within cs2: >=9216 B)
    // D==1 layout:
    float*  slg = sx + NE;                      // [NE] v*log(v+eps)

    const int w0 = blockIdx.x * TW;
    const int h0 = blockIdx.y * TH;
    const float* xp = x + (size_t)bc * H * W;
    const int tid = threadIdx.y * 64 + threadIdx.x;
    const int tx = threadIdx.x;
    const int ty = threadIdx.y;

    // ---- Staging: element-pair global loads, b64 LDS writes. ----
    float v0b[NI2], v1b[NI2];
#pragma unroll
    for (int i = 0; i < NI2; ++i) {
        const int e0 = 2 * (tid + i * 512);
        float v0 = 0.f, v1 = 0.f;
        if (e0 < NE) {
            const int r  = e0 / LW;          // e0, LW even -> cc even
            const int cc = e0 - r * LW;
            const int gh = h0 - PAD + r;
            const int gw = w0 - PAD + cc;
            if (gh >= 0 && gh < H) {
                if constexpr ((PAD & 1) == 0) {
                    if (gw >= 0 && gw + 1 < W) {        // aligned float2 path
                        const float2 v = *(const float2*)&xp[gh * W + gw];
                        v0 = v.x; v1 = v.y;
                    } else {
                        if (gw >= 0 && gw < W)         v0 = xp[gh * W + gw];
                        if (gw + 1 >= 0 && gw + 1 < W) v1 = xp[gh * W + gw + 1];
                    }
                } else {
                    if (gw >= 0 && gw < W)         v0 = xp[gh * W + gw];
                    if (gw + 1 >= 0 && gw + 1 < W) v1 = xp[gh * W + gw + 1];
                }
            }
        }
        v0b[i] = v0; v1b[i] = v1;
    }
#pragma unroll
    for (int i = 0; i < NI2; ++i) {
        const int e0 = 2 * (tid + i * 512);
        if (e0 < NE) {
            *(float2*)&sx[e0] = make_float2(v0b[i], v1b[i]);
            if constexpr (D == 1)
                *(float2*)&slg[e0] = make_float2(v0b[i] * __logf(v0b[i] + EPS),
                                                 v1b[i] * __logf(v1b[i] + EPS));
        }
    }
    __syncthreads();

    const size_t fs = (size_t)H * W;
    float* op = out + (size_t)bc * 4 * fs + w0 + tx;

    if constexpr (K <= 9) {
        // ---- D=1: register path, two rows per thread. ----
        auto d1row = [&](int row) {
            const float* bx = sx  + row * LW + tx;
            const float* bl = slg + row * LW + tx;
            float s = 0.f, s2 = 0.f, sl = 0.f, ta[9];
#pragma unroll
            for (int mi = 0; mi < 3; ++mi)
#pragma unroll
                for (int mj = 0; mj < 3; ++mj) {
                    const float v = bx[mi * LW + mj];
                    ta[mi * 3 + mj] = v;
                    s += v; s2 = fmaf(v, v, s2);
                    sl += bl[mi * LW + mj];
                }
            const float mu = s * INVK;
            float sad = 0.f;
#pragma unroll
            for (int i = 0; i < 9; ++i) sad += fabsf(ta[i] - mu);
            const float energy   = s2 * INVK;
            const float var      = fmaxf(energy - mu * mu, 0.f);
            const float sd       = __builtin_amdgcn_sqrtf(var * UNB) + EPS;
            const float contrast = var * __builtin_amdgcn_rcpf(sd * sd);
            const float entropy  = -sl * INVK;
            const float homog    = __builtin_amdgcn_rcpf(fmaf(sad, INVK, 1.0f));
            const size_t ro = (size_t)(h0 + row) * W;
            __builtin_nontemporal_store((contrast + EPS) * INV_SQRT_E, &op[0 * fs + ro]);
            __builtin_nontemporal_store((energy   + EPS) * INV_SQRT_E, &op[1 * fs + ro]);
            __builtin_nontemporal_store((entropy  + EPS) * INV_SQRT_E, &op[2 * fs + ro]);
            __builtin_nontemporal_store((homog    + EPS) * INV_SQRT_E, &op[3 * fs + ro]);
        };
        d1row(ty);
        __builtin_amdgcn_sched_barrier(0);
        d1row(ty + 8);
        return;
    } else {
        // ---- Vertical stage: residue-class chain walkers (col-pair b64). ----
        if constexpr (D == 4) {
            constexpr int NW = LW / 2;               // 48 col-pairs
            if (tid < 4 * NW) {
                const int p = tid / NW, c2 = (tid - p * NW) * 2;
                vchain<4, 4, 12, LW, KS>(sx, (float*)cs2, cs1, p, c2);
            }
        } else if constexpr (D == 3) {
            constexpr int NW = LW / 2;               // 41 col-pairs
            if (tid < 3 * NW) {
                const int p = tid / NW, c2 = (tid - p * NW) * 2;
                if (p == 0) vchain<3, 6, 12, LW, KS>(sx, (float*)cs2, cs1, 0, c2);
                else        vchain<3, 5, 11, LW, KS>(sx, (float*)cs2, cs1, p, c2);
            }
        } else {  // D == 2: half-chains rows {0,2,4,6},{1,3,5,7},{8..14},{9..15}
            constexpr int NW = LW / 2;               // 36 col-pairs
            if (tid < 4 * NW) {
                const int p = tid / NW, c2 = (tid - p * NW) * 2;
                const int r0 = (p & 1) + ((p >> 1) << 3);
                vchain<2, 4, 8, LW, KS>(sx, (float*)cs2, cs1, r0, c2);
            }
        }
        __syncthreads();

        // ---- Horizontal stage: two rows per thread (named scalars). ----
        float s2a, sla, mua, s2b, slb, mub;
        {
            const int row = ty;
            float s = 0.f, s2 = 0.f, sl = 0.f;
            const float2* q2 = cs2 + row * LW + tx;
            const float*  q1 = cs1 + row * LW + tx;
#pragma unroll
            for (int mj = 0; mj < KS; ++mj) {
                const float2 q = q2[mj * D];
                s += q.x; s2 += q.y; sl += q1[mj * D];
            }
            s2a = s2; sla = sl; mua = s * INVK;
        }
        __builtin_amdgcn_sched_barrier(0);
        {
            const int row = ty + 8;
            float s = 0.f, s2 = 0.f, sl = 0.f;
            const float2* q2 = cs2 + row * LW + tx;
            const float*  q1 = cs1 + row * LW + tx;
#pragma unroll
            for (int mj = 0; mj < KS; ++mj) {
                const float2 q = q2[mj * D];
                s += q.x; s2 += q.y; sl += q1[mj * D];
            }
            s2b = s2; slb = sl; mub = s * INVK;
        }
        __syncthreads();                 // cs reads done; muP aliases cs2
        muP[ty * 64 + tx] = mua;
        muP[(ty + 8) * 64 + tx] = mub;
        __syncthreads();

        // ---- SAD: chain walkers. ----
        if constexpr (D == 4) {
            if (tid < 128) {             // 4 chains x 32 col-pairs, b64
                const int p = tid >> 5, c2 = (tid & 31) * 2;
                sadchain_pair<4, 4, 12, LW, KS>(sx, muP, sadP, p, c2);
            }
        } else if constexpr (D == 2) {
            if (tid < 128) {             // 4 half-chains x 32 col-pairs, b64
                const int p = tid >> 5, c2 = (tid & 31) * 2;
                const int r0 = (p & 1) + ((p >> 1) << 3);
                sadchain_pair<2, 4, 8, LW, KS>(sx, muP, sadP, r0, c2);
            }
        } else {  // D == 3
            if (tid < 192) {             // 3 chains x 64 cols, b32
                const int p = tid >> 6, c = tid & 63;
                if (p == 0) sadchain_scalar<3, 6, 12, LW, KS>(sx, muP, sadP, 0, c);
                else        sadchain_scalar<3, 5, 11, LW, KS>(sx, muP, sadP, p, c);
            }
        }
        __syncthreads();

        // ---- Epilogue: two rows per thread. ----
        {
            const int row = ty;
            const float sad = sadP[row * 64 + tx];
            const float energy   = s2a * INVK;
            const float var      = fmaxf(energy - mua * mua, 0.f);
            const float sd       = __builtin_amdgcn_sqrtf(var * UNB) + EPS;
            const float contrast = var * __builtin_amdgcn_rcpf(sd * sd);
            const float entropy  = -sla * INVK;
            const float homog    = __builtin_amdgcn_rcpf(fmaf(sad, INVK, 1.0f));
            const size_t ro = (size_t)(h0 + row) * W;
            __builtin_nontemporal_store((contrast + EPS) * INV_SQRT_E, &op[0 * fs + ro]);
            __builtin_nontemporal_store((energy   + EPS) * INV_SQRT_E, &op[1 * fs + ro]);
            __builtin_nontemporal_store((entropy  + EPS) * INV_SQRT_E, &op[2 * fs + ro]);
            __builtin_nontemporal_store((homog    + EPS) * INV_SQRT_E, &op[3 * fs + ro]);
        }
        {
            const int row = ty + 8;
            const float sad = sadP[row * 64 + tx];
            const float energy   = s2b * INVK;
            const float var      = fmaxf(energy - mub * mub, 0.f);
            const float sd       = __builtin_amdgcn_sqrtf(var * UNB) + EPS;
            const float contrast = var * __builtin_amdgcn_rcpf(sd * sd);
            const float entropy  = -slb * INVK;
            const float homog    = __builtin_amdgcn_rcpf(fmaf(sad, INVK, 1.0f));
            const size_t ro = (size_t)(h0 + row) * W;
            __builtin_nontemporal_store((contrast + EPS) * INV_SQRT_E, &op[0 * fs + ro]);
            __builtin_nontemporal_store((energy   + EPS) * INV_SQRT_E, &op[1 * fs + ro]);
            __builtin_nontemporal_store((entropy  + EPS) * INV_SQRT_E, &op[2 * fs + ro]);
            __builtin_nontemporal_store((homog    + EPS) * INV_SQRT_E, &op[3 * fs + ro]);
        }
    }
}

__global__ __launch_bounds__(512, 8) void tex_fused(
    const float* __restrict__ x, float* __restrict__ out, int H, int W)
{
    extern __shared__ __align__(16) char smem[];
    const int dz = blockIdx.z & 3;       // dilation in fast bits: co-resident
    const int bc = blockIdx.z >> 2;      // blocks on a CU mix D1..D4
    const size_t per = (size_t)8 * 4 * H * W;
    switch (dz) {
        case 0: body<4>(x, out + 3 * per, smem, bc, H, W); break;
        case 1: body<3>(x, out + 2 * per, smem, bc, H, W); break;
        case 2: body<2>(x, out + 1 * per, smem, bc, H, W); break;
        default: body<1>(x, out + 0 * per, smem, bc, H, W); break;
    }
}

extern "C" void kernel_launch(void* const* d_in, const int* in_sizes, int n_in,
                              void* d_out, int out_size, void* d_ws, size_t ws_size,
                              hipStream_t stream) {
    const float* x = (const float*)d_in[0];
    float* out = (float*)d_out;

    const int H = 256, W = 256;
    // Per-D LDS (TH=16): sx LH*LW*4 + cs2 16*LW*8 + cs1 16*LW*4
    //   D=4: LH=48, LW=96: 18432 + 12288 + 6144 = 36864 (max) -> 4 blocks/CU
    //   D=3: LH=34, LW=82: 11152 + 10496 + 5248 = 26896
    //   D=2: LH=24, LW=72:  6912 +  9216 + 4608 = 20736
    //   D=1: LH=18, LW=66:  4752 + 4752 (slg)   =  9504
    const size_t smem_bytes = 36864;

    dim3 blk(64, 8, 1);
    dim3 grd(W / 64, H / 16, 8 * 4);     // 4 x-tiles, 16 y-tiles, (bc x dz)
    tex_fused<<<grd, blk, smem_bytes, stream>>>(x, out, H, W);
}

// Round 6
// 77.456 us; speedup vs baseline: 1.0918x; 1.0918x over previous
//
#include <hip/hip_runtime.h>
#include <cstddef>

#define EPS 1e-6f
constexpr float INV_SQRT_E = 0.6065306597126334f;  // exp(-0.5*THETA^2), THETA=1

// R19 = R17 (verified 77.2 us) + phase-overlap restructure ONLY.
// Evidence R15-R18: instruction cuts are time-neutral; wave-count cuts
// regress => kernel is latency/BARRIER-structure bound, not issue-bound.
// Changes vs R17 (all math bit-identical):
//  1. SAD waves (ty<4) compute their own mu from cs2.x (KS b32 reads/row,
//     8B stride = 2-way bank = free) -- no muP exchange, no dependency on
//     the horizontal stage.
//  2. Role-split: after vertical sync, waves 0-3 do mu+SAD while waves 4-7
//     concurrently do horizontal for 2 rows each; after one sync they do
//     the epilogue+stores for both rows. Longest phase now overlaps.
//  3. Barriers 5 -> 3. sadP aliases the dead slg plane (slg fully consumed
//     by vertical pass-2 before the preceding sync). LDS unchanged 39,936 B
//     -> 4 blocks/CU = 32 waves/CU.
template <int D>
__device__ __forceinline__ void body(const float* __restrict__ x,
                                     float* __restrict__ out,
                                     char* smem, int bc, int H, int W)
{
    constexpr int PAD = D * D;          // halo per side
    constexpr int KS  = 2 * D + 1;      // taps per axis
    constexpr int K   = KS * KS;        // patch size
    constexpr int TW  = 64, TH = 8;
    constexpr int LW  = TW + 2 * PAD;   // always even
    constexpr int LH  = TH + 2 * PAD;
    constexpr int NE  = LH * LW;        // always even
    constexpr int NI2 = (NE + 1023) / 1024;
    constexpr float INVK = 1.0f / (float)K;
    constexpr float UNB  = (float)K / (float)(K - 1);

    float*  sx  = (float*)smem;                 // [NE] v
    float*  slg = sx + NE;                      // [NE] v*log(v+eps)
    float2* cs2 = (float2*)(slg + NE);          // [TH*LW] {col_s, col_s2}
    float*  cs1 = (float*)(cs2 + TH * LW);      // [TH*LW] col_sl
    // sadP aliases slg (dead after vertical pass-2; needs 2048 B <= NE*4).
    float*  sadP = slg;                         // [TH*64]

    const int w0 = blockIdx.x * TW;
    const int h0 = blockIdx.y * TH;
    const float* xp = x + (size_t)bc * H * W;
    const int tid = threadIdx.y * 64 + threadIdx.x;

    // ---- Staging: batched global loads (element pairs), b64 LDS writes. ----
    float v0b[NI2], v1b[NI2];
    #pragma unroll
    for (int i = 0; i < NI2; ++i) {
        const int e0 = 2 * (tid + i * 512);
        float v0 = 0.0f, v1 = 0.0f;
        if (e0 < NE) {
            const int r  = e0 / LW;          // e0, LW even -> cc even
            const int cc = e0 - r * LW;
            const int gh = h0 - PAD + r;
            const int gw = w0 - PAD + cc;
            if (gh >= 0 && gh < H) {
                if constexpr ((PAD & 1) == 0) {
                    // gw even: aligned float2 global fast-path
                    if (gw >= 0 && gw + 1 < W) {
                        const float2 v = *(const float2*)&xp[gh * W + gw];
                        v0 = v.x; v1 = v.y;
                    } else {
                        if (gw >= 0 && gw < W)         v0 = xp[gh * W + gw];
                        if (gw + 1 >= 0 && gw + 1 < W) v1 = xp[gh * W + gw + 1];
                    }
                } else {
                    if (gw >= 0 && gw < W)         v0 = xp[gh * W + gw];
                    if (gw + 1 >= 0 && gw + 1 < W) v1 = xp[gh * W + gw + 1];
                }
            }
        }
        v0b[i] = v0; v1b[i] = v1;
    }
    #pragma unroll
    for (int i = 0; i < NI2; ++i) {
        const int e0 = 2 * (tid + i * 512);
        if (e0 < NE) {
            *(float2*)&sx[e0]  = make_float2(v0b[i], v1b[i]);
            *(float2*)&slg[e0] = make_float2(v0b[i] * __logf(v0b[i] + EPS),
                                             v1b[i] * __logf(v1b[i] + EPS));
        }
    }
    __syncthreads();

    const int tx = threadIdx.x;
    const int ty = threadIdx.y;

    if constexpr (K <= 9) {
        // ---- D=1: single pass, taps cached in registers. ----
        const float* bx = sx  + ty * LW + tx;
        const float* bl = slg + ty * LW + tx;
        float s = 0.f, s2 = 0.f, sl = 0.f, ta[K];
        #pragma unroll
        for (int mi = 0; mi < KS; ++mi)
            #pragma unroll
            for (int mj = 0; mj < KS; ++mj) {
                const float v = bx[mi * LW + mj];
                ta[mi * KS + mj] = v;
                s  += v;
                s2  = fmaf(v, v, s2);
                sl += bl[mi * LW + mj];
            }
        const float mu = s * INVK;
        float sad = 0.f;
        #pragma unroll
        for (int i = 0; i < K; ++i) sad += fabsf(ta[i] - mu);

        const float energy   = s2 * INVK;
        const float var      = fmaxf(energy - mu * mu, 0.f);
        const float sd       = __builtin_amdgcn_sqrtf(var * UNB) + EPS;
        const float contrast = var * __builtin_amdgcn_rcpf(sd * sd);
        const float entropy  = -sl * INVK;
        const float homog    = __builtin_amdgcn_rcpf(fmaf(sad, INVK, 1.0f));
        const size_t fs = (size_t)H * W;
        const size_t ro = (size_t)(h0 + ty) * W;
        float* op = out + (size_t)bc * 4 * fs + w0 + tx;
        __builtin_nontemporal_store((contrast + EPS) * INV_SQRT_E, &op[0 * fs + ro]);
        __builtin_nontemporal_store((energy   + EPS) * INV_SQRT_E, &op[1 * fs + ro]);
        __builtin_nontemporal_store((entropy  + EPS) * INV_SQRT_E, &op[2 * fs + ro]);
        __builtin_nontemporal_store((homog    + EPS) * INV_SQRT_E, &op[3 * fs + ro]);
        return;
    } else {
        // ---- Vertical stage: column-PAIR (b64) pair-walk, plane-split.
        //  Row pairs: D=2: (0,2)(1,3)(4,6)(5,7)  D=3: (0,3)(1,4)(2,5)+{6,7}
        //  D=4: (0,4)(1,5)(2,6)(3,7)
        constexpr int HW2 = LW / 2;
        if (tid < 4 * HW2) {
            const int p  = tid / HW2;
            const int c2 = (tid - p * HW2) * 2;
            if (!(D == 3 && p == 3)) {
                const int vA = (D == 2) ? ((p < 2) ? p : p + 2) : p;
                const int vB = vA + D;
                // pass 1: sx (sum + sumsq), 8 live accumulators
                const float2* cx = (const float2*)(sx + vA * LW + c2);
                float sA0=0,sA1=0,qA0=0,qA1=0,sB0=0,sB1=0,qB0=0,qB1=0;
                #pragma unroll
                for (int t = 0; t <= KS; ++t) {
                    const float2 v = cx[t * D * HW2];
                    if (t < KS) { sA0 += v.x; sA1 += v.y;
                                  qA0 = fmaf(v.x,v.x,qA0); qA1 = fmaf(v.y,v.y,qA1); }
                    if (t >= 1) { sB0 += v.x; sB1 += v.y;
                                  qB0 = fmaf(v.x,v.x,qB0); qB1 = fmaf(v.y,v.y,qB1); }
                }
                // pass 2: slg, 4 live accumulators
                const float2* cl = (const float2*)(slg + vA * LW + c2);
                float lA0=0,lA1=0,lB0=0,lB1=0;
                #pragma unroll
                for (int t = 0; t <= KS; ++t) {
                    const float2 g = cl[t * D * HW2];
                    if (t < KS) { lA0 += g.x; lA1 += g.y; }
                    if (t >= 1) { lB0 += g.x; lB1 += g.y; }
                }
                *(float4*)&cs2[vA * LW + c2] = make_float4(sA0, qA0, sA1, qA1);
                *(float4*)&cs2[vB * LW + c2] = make_float4(sB0, qB0, sB1, qB1);
                *(float2*)&cs1[vA * LW + c2] = make_float2(lA0, lA1);
                *(float2*)&cs1[vB * LW + c2] = make_float2(lB0, lB1);
            } else {            // D=3 leftover rows 6,7: independent col-pair walks
                #pragma unroll
                for (int rr = 6; rr <= 7; ++rr) {
                    const float2* cx = (const float2*)(sx  + rr * LW + c2);
                    const float2* cl = (const float2*)(slg + rr * LW + c2);
                    float s0=0,s1=0,q0=0,q1=0,l0=0,l1=0;
                    #pragma unroll
                    for (int mi = 0; mi < KS; ++mi) {
                        const float2 v = cx[mi * D * HW2];
                        const float2 g = cl[mi * D * HW2];
                        s0 += v.x; s1 += v.y;
                        q0 = fmaf(v.x,v.x,q0); q1 = fmaf(v.y,v.y,q1);
                        l0 += g.x; l1 += g.y;
                    }
                    *(float4*)&cs2[rr * LW + c2] = make_float4(s0, q0, s1, q1);
                    *(float2*)&cs1[rr * LW + c2] = make_float2(l0, l1);
                }
            }
        }
        __syncthreads();   // slg fully consumed; cs2/cs1 ready

        // ==== Overlapped phase: waves 0-3 SAD (self-mu) || waves 4-7 ====
        // ==== horizontal for 2 rows each.                             ====
        float s2a, sla, mua, s2b, slb, mub;   // live only in waves 4-7
        if (ty < 4) {
            const int o = ty;
            if (!(D == 3 && o == 3)) {
                const int rA = (D == 2) ? ((o < 2) ? o : o + 2) : o;
                const int rB = rA + D;
                // self-mu from cs2.x (b32 reads, 8B stride: 2-way = free)
                float sA = 0.f, sB = 0.f;
                const float* cA = (const float*)(cs2 + rA * LW + tx);
                const float* cB = (const float*)(cs2 + rB * LW + tx);
                #pragma unroll
                for (int mj = 0; mj < KS; ++mj) {
                    sA += cA[2 * mj * D];
                    sB += cB[2 * mj * D];
                }
                const float muA = sA * INVK;
                const float muB = sB * INVK;
                float sadA = 0.f, sadB = 0.f;
                const float* bp = sx + rA * LW + tx;
                #pragma unroll
                for (int mj = 0; mj < KS; ++mj) {
                    const float* cp = bp + mj * D;
                    #pragma unroll
                    for (int t = 0; t <= KS; ++t) {
                        const float v = cp[t * D * LW];
                        if (t < KS) sadA += fabsf(v - muA);
                        if (t >= 1) sadB += fabsf(v - muB);
                    }
                }
                sadP[rA * 64 + tx] = sadA;
                sadP[rB * 64 + tx] = sadB;
            } else {             // D=3 leftover rows 6,7: full K walks
                #pragma unroll
                for (int rr = 6; rr <= 7; ++rr) {
                    float sr = 0.f;
                    const float* cR = (const float*)(cs2 + rr * LW + tx);
                    #pragma unroll
                    for (int mj = 0; mj < KS; ++mj) sr += cR[2 * mj * D];
                    const float mur = sr * INVK;
                    const float* bp = sx + rr * LW + tx;
                    float sd = 0.f;
                    #pragma unroll
                    for (int mi = 0; mi < KS; ++mi)
                        #pragma unroll
                        for (int mj = 0; mj < KS; ++mj)
                            sd += fabsf(bp[mi * D * LW + mj * D] - mur);
                    sadP[rr * 64 + tx] = sd;
                }
            }
        } else {
            // horizontal for rows r0 = 2*(ty-4), r1 = r0+1 (named scalars)
            const int r0 = 2 * (ty - 4);
            {
                float s = 0.f, s2 = 0.f, sl = 0.f;
                const float2* q2 = cs2 + r0 * LW + tx;
                const float*  q1 = cs1 + r0 * LW + tx;
                #pragma unroll
                for (int mj = 0; mj < KS; ++mj) {
                    const float2 q = q2[mj * D];
                    s += q.x; s2 += q.y; sl += q1[mj * D];
                }
                s2a = s2; sla = sl; mua = s * INVK;
            }
            {
                float s = 0.f, s2 = 0.f, sl = 0.f;
                const float2* q2 = cs2 + (r0 + 1) * LW + tx;
                const float*  q1 = cs1 + (r0 + 1) * LW + tx;
                #pragma unroll
                for (int mj = 0; mj < KS; ++mj) {
                    const float2 q = q2[mj * D];
                    s += q.x; s2 += q.y; sl += q1[mj * D];
                }
                s2b = s2; slb = sl; mub = s * INVK;
            }
        }
        __syncthreads();   // sadP complete; horizontal results in regs

        // ---- Epilogue: waves 4-7 only, 2 rows per thread. ----
        if (ty >= 4) {
            const int r0 = 2 * (ty - 4);
            const size_t fs = (size_t)H * W;
            float* op = out + (size_t)bc * 4 * fs + w0 + tx;
            {
                const float sad = sadP[r0 * 64 + tx];
                const float energy   = s2a * INVK;
                const float var      = fmaxf(energy - mua * mua, 0.f);
                const float sd       = __builtin_amdgcn_sqrtf(var * UNB) + EPS;
                const float contrast = var * __builtin_amdgcn_rcpf(sd * sd);
                const float entropy  = -sla * INVK;
                const float homog    = __builtin_amdgcn_rcpf(fmaf(sad, INVK, 1.0f));
                const size_t ro = (size_t)(h0 + r0) * W;
                __builtin_nontemporal_store((contrast + EPS) * INV_SQRT_E, &op[0 * fs + ro]);
                __builtin_nontemporal_store((energy   + EPS) * INV_SQRT_E, &op[1 * fs + ro]);
                __builtin_nontemporal_store((entropy  + EPS) * INV_SQRT_E, &op[2 * fs + ro]);
                __builtin_nontemporal_store((homog    + EPS) * INV_SQRT_E, &op[3 * fs + ro]);
            }
            {
                const float sad = sadP[(r0 + 1) * 64 + tx];
                const float energy   = s2b * INVK;
                const float var      = fmaxf(energy - mub * mub, 0.f);
                const float sd       = __builtin_amdgcn_sqrtf(var * UNB) + EPS;
                const float contrast = var * __builtin_amdgcn_rcpf(sd * sd);
                const float entropy  = -slb * INVK;
                const float homog    = __builtin_amdgcn_rcpf(fmaf(sad, INVK, 1.0f));
                const size_t ro = (size_t)(h0 + r0 + 1) * W;
                __builtin_nontemporal_store((contrast + EPS) * INV_SQRT_E, &op[0 * fs + ro]);
                __builtin_nontemporal_store((energy   + EPS) * INV_SQRT_E, &op[1 * fs + ro]);
                __builtin_nontemporal_store((entropy  + EPS) * INV_SQRT_E, &op[2 * fs + ro]);
                __builtin_nontemporal_store((homog    + EPS) * INV_SQRT_E, &op[3 * fs + ro]);
            }
        }
    }
}

__global__ __launch_bounds__(512, 8) void tex_fused(
    const float* __restrict__ x, float* __restrict__ out, int H, int W)
{
    extern __shared__ __align__(16) char smem[];
    const int dz = blockIdx.z & 3;       // dilation in fast bits: co-resident
    const int bc = blockIdx.z >> 2;      // blocks on a CU mix D1..D4
    const size_t per = (size_t)8 * 4 * H * W;
    switch (dz) {
        case 0: body<4>(x, out + 3 * per, smem, bc, H, W); break;
        case 1: body<3>(x, out + 2 * per, smem, bc, H, W); break;
        case 2: body<2>(x, out + 1 * per, smem, bc, H, W); break;
        default: body<1>(x, out + 0 * per, smem, bc, H, W); break;
    }
}

extern "C" void kernel_launch(void* const* d_in, const int* in_sizes, int n_in,
                              void* d_out, int out_size, void* d_ws, size_t ws_size,
                              hipStream_t stream) {
    const float* x = (const float*)d_in[0];
    float* out = (float*)d_out;

    const int H = 256, W = 256;
    // Per-D LDS (TH=8, PAD=D*D): 2 b32 planes LH*LW*8 + cs2 TH*LW*8 + cs1 TH*LW*4
    //   D=4: LH=40, LW=96: 30720 + 6144 + 3072 = 39936  (max) -> 4 blocks/CU
    //   D=3: LH=26, LW=82: 17056 + 5248 + 2624 = 24928
    //   D=2: LH=16, LW=72:  9216 + 4608 + 2304 = 16128
    //   D=1: LH=10, LW=66:  5280 (register path; cs unused)
    // sadP aliases slg (no extra LDS).
    const size_t smem_bytes = 39936;

    dim3 blk(64, 8, 1);
    dim3 grd(W / 64, H / 8, 8 * 4);      // 4 x-tiles, 32 y-tiles, (bc x dz)
    tex_fused<<<grd, blk, smem_bytes, stream>>>(x, out, H, W);
}